// Round 4
// baseline (294.327 us; speedup 1.0000x reference)
//
#include <hip/hip_runtime.h>

#define T_DIM 512
#define B_DIM 4096
#define F_DIM 16
#define L_DIM 4

// ---------------- fast activations (exp2/rcp based, ~1 ulp) -----------------
__device__ __forceinline__ float fast_sigmoid(float x) {
  return __builtin_amdgcn_rcpf(1.0f + __builtin_amdgcn_exp2f(-1.44269504089f * x));
}
__device__ __forceinline__ float fast_tanh(float x) {
  return 1.0f - 2.0f * __builtin_amdgcn_rcpf(1.0f + __builtin_amdgcn_exp2f(2.88539008178f * x));
}

// lane(i) <- lane(i-1) within 16-lane DPP rows; VALU op, stays off the LDS
// pipe. Row-boundary lanes get 0 (bound_ctrl) — those are l=0 lanes which
// ignore hin anyway (wih=0).
__device__ __forceinline__ float dpp_prev(float v) {
  int r = __builtin_amdgcn_update_dpp(0, __builtin_bit_cast(int, v),
                                      0x111 /*row_shr:1*/, 0xf, 0xf, true);
  return __builtin_bit_cast(float, r);
}

// ---------------- phase 1: gx0[t,b,g] = x[t,b,:]·Wih0[g,:] + bih0 + bhh0 ----
__global__ __launch_bounds__(256) void gx0_kernel(
    const float* __restrict__ x, const float* __restrict__ Wih0,
    const float* __restrict__ bih, const float* __restrict__ bhh,
    float4* __restrict__ gx) {
  int idx = blockIdx.x * 256 + threadIdx.x;          // idx = t*B + b, exact grid
  const float4* xr = (const float4*)x + (size_t)idx * 4;
  float4 xv0 = xr[0], xv1 = xr[1], xv2 = xr[2], xv3 = xr[3];
  float xs[16];
  *(float4*)&xs[0]  = xv0; *(float4*)&xs[4]  = xv1;
  *(float4*)&xs[8]  = xv2; *(float4*)&xs[12] = xv3;
  float acc[4];
#pragma unroll
  for (int g = 0; g < 4; ++g) {
    acc[g] = bih[g] + bhh[g];
    const float* w = Wih0 + g * 16;   // uniform address -> scalar loads
#pragma unroll
    for (int i = 0; i < 16; ++i) acc[g] = fmaf(w[i], xs[i], acc[g]);
  }
  gx[idx] = make_float4(acc[0], acc[1], acc[2], acc[3]);
}

// ---------------- phase 2: layer-skewed scan ---------------------------------
// Lane 4*cb + l handles (chain b, layer l) at time t = k - l. h_{l-1}(t) comes
// from lane-1 via DPP row_shr:1 (produced there in iteration k-1).
// 4096 chains x 4 layers = 16384 threads = 256 waves = 1 wave/CU.
// __launch_bounds__(64,1): one wave per EU is all the parallelism that exists,
// so let the register allocator keep the full 8-deep float4 prefetch ring
// resident (32 VGPRs) instead of collapsing it (R2: VGPR_Count=44 -> exposed
// ~200cy load latency per iteration).
__global__ __launch_bounds__(64, 1) void lstm_scan_skew(
    const float4* __restrict__ gx,    // [T,B] of float4 (i,f,g,o), bias folded
    const float* __restrict__ Wrest,  // [3,4]
    const float* __restrict__ Whh,    // [4,4]
    const float* __restrict__ bih, const float* __restrict__ bhh,
    float* __restrict__ out) {
  const int lane = threadIdx.x;                    // 0..63
  const int l = lane & 3;                          // layer
  const int b = blockIdx.x * 16 + (lane >> 2);     // chain 0..4095
  const bool l0 = (l == 0);
  const float gsel = l0 ? 1.0f : 0.0f;             // gx only feeds layer 0

  float wih[4], whh[4], base[4];
#pragma unroll
  for (int g = 0; g < 4; ++g) {
    whh[g]  = Whh[l * 4 + g];
    wih[g]  = l0 ? 0.0f : Wrest[(l - 1) * 4 + g];
    base[g] = l0 ? 0.0f : (bih[l * 4 + g] + bhh[l * 4 + g]);
  }

  const float4* __restrict__ pg = gx + b;          // lane base; step = B_DIM
  float* __restrict__ po = out + b;

  float h = 0.f, c = 0.f;

  // 8-deep prefetch ring; quad lanes load the same address (HW broadcast).
  float4 gbuf[8];
#pragma unroll
  for (int j = 0; j < 8; ++j) gbuf[j] = pg[(size_t)j * B_DIM];

  // One step. `guard` is a compile-time constant at every call site.
  auto cell = [&](int k, int j, bool guard) {
    float4 gq = gbuf[j];
    const int tp = k + 8;
    if (tp < T_DIM)                                 // wave-uniform branch; drain
      gbuf[j] = pg[(size_t)tp * B_DIM];             // chunk's gq is never consumed

    float hin = dpp_prev(h);                       // h_{l-1}(t)

    float g0 = fmaf(whh[0], h, fmaf(wih[0], hin, fmaf(gsel, gq.x, base[0])));
    float g1 = fmaf(whh[1], h, fmaf(wih[1], hin, fmaf(gsel, gq.y, base[1])));
    float g2 = fmaf(whh[2], h, fmaf(wih[2], hin, fmaf(gsel, gq.z, base[2])));
    float g3 = fmaf(whh[3], h, fmaf(wih[3], hin, fmaf(gsel, gq.w, base[3])));

    float i_ = fast_sigmoid(g0);
    float f_ = fast_sigmoid(g1);
    float gg = fast_tanh(g2);
    float o_ = fast_sigmoid(g3);
    float cn = fmaf(f_, c, i_ * gg);
    float hn = o_ * fast_tanh(cn);

    if (guard) {
      const int t = k - l;
      const bool valid = (unsigned)t < (unsigned)T_DIM;
      c = valid ? cn : c;
      h = valid ? hn : h;
      if (l == 3 && valid) po[(size_t)t * B_DIM] = hn;
    } else {
      c = cn;
      h = hn;
      if (l == 3) po[(size_t)(k - 3) * B_DIM] = hn;
    }
  };

  // warm-up: k=0..7 (some lanes still at t<0)
#pragma unroll
  for (int j = 0; j < 8; ++j) cell(j, j, true);
  // body: k=8..511 — every lane's t=k-l is in [0,511]; no guards
  for (int k0 = 8; k0 < T_DIM; k0 += 8) {
#pragma unroll
    for (int j = 0; j < 8; ++j) cell(k0 + j, j, false);
  }
  // drain: k=512..519 (lanes l>0 finish t=509..511)
#pragma unroll
  for (int j = 0; j < 8; ++j) cell(T_DIM + j, j, true);

  // hn, cn: lane (b,l) holds h_l(T-1), c_l(T-1)
  po[(size_t)T_DIM * B_DIM + (size_t)l * B_DIM] = h;
  po[(size_t)T_DIM * B_DIM + (size_t)L_DIM * B_DIM + (size_t)l * B_DIM] = c;
}

// ---------------- fallback (no workspace): fused, unskewed -------------------
__global__ __launch_bounds__(64) void lstm_scan_fused(
    const float* __restrict__ x, const float* __restrict__ Wih0,
    const float* __restrict__ Wrest, const float* __restrict__ Whh,
    const float* __restrict__ bih, const float* __restrict__ bhh,
    float* __restrict__ out) {
  const int b = blockIdx.x * 64 + threadIdx.x;
  float whh_[4][4];
#pragma unroll
  for (int l = 0; l < 4; ++l)
#pragma unroll
    for (int g = 0; g < 4; ++g) whh_[l][g] = Whh[l * 4 + g];
  float wih_[3][4], base_[3][4];
#pragma unroll
  for (int l = 0; l < 3; ++l)
#pragma unroll
    for (int g = 0; g < 4; ++g) {
      wih_[l][g]  = Wrest[l * 4 + g];
      base_[l][g] = bih[(l + 1) * 4 + g] + bhh[(l + 1) * 4 + g];
    }
  float base0[4], wih0r[4][16];
#pragma unroll
  for (int g = 0; g < 4; ++g) {
    base0[g] = bih[g] + bhh[g];
#pragma unroll
    for (int i = 0; i < 16; ++i) wih0r[g][i] = Wih0[g * 16 + i];
  }
  float h[4] = {0.f,0.f,0.f,0.f}, c[4] = {0.f,0.f,0.f,0.f};
  for (int t = 0; t < T_DIM; ++t) {
    const float4* xr = (const float4*)x + ((size_t)t * B_DIM + b) * 4;
    float xs[16];
    *(float4*)&xs[0] = xr[0]; *(float4*)&xs[4] = xr[1];
    *(float4*)&xs[8] = xr[2]; *(float4*)&xs[12] = xr[3];
    float a0 = base0[0], a1 = base0[1], a2 = base0[2], a3 = base0[3];
#pragma unroll
    for (int i = 0; i < 16; ++i) {
      a0 = fmaf(wih0r[0][i], xs[i], a0);
      a1 = fmaf(wih0r[1][i], xs[i], a1);
      a2 = fmaf(wih0r[2][i], xs[i], a2);
      a3 = fmaf(wih0r[3][i], xs[i], a3);
    }
    float i_ = fast_sigmoid(fmaf(whh_[0][0], h[0], a0));
    float f_ = fast_sigmoid(fmaf(whh_[0][1], h[0], a1));
    float gg = fast_tanh(fmaf(whh_[0][2], h[0], a2));
    float o_ = fast_sigmoid(fmaf(whh_[0][3], h[0], a3));
    c[0] = fmaf(f_, c[0], i_ * gg);
    h[0] = o_ * fast_tanh(c[0]);
#pragma unroll
    for (int l = 1; l < 4; ++l) {
      float hin = h[l - 1];
      float gi = fmaf(whh_[l][0], h[l], fmaf(wih_[l-1][0], hin, base_[l-1][0]));
      float gf = fmaf(whh_[l][1], h[l], fmaf(wih_[l-1][1], hin, base_[l-1][1]));
      float gG = fmaf(whh_[l][2], h[l], fmaf(wih_[l-1][2], hin, base_[l-1][2]));
      float go = fmaf(whh_[l][3], h[l], fmaf(wih_[l-1][3], hin, base_[l-1][3]));
      float ii = fast_sigmoid(gi), ff = fast_sigmoid(gf);
      float gg2 = fast_tanh(gG), oo = fast_sigmoid(go);
      c[l] = fmaf(ff, c[l], ii * gg2);
      h[l] = oo * fast_tanh(c[l]);
    }
    out[(size_t)t * B_DIM + b] = h[3];
  }
#pragma unroll
  for (int l = 0; l < 4; ++l) {
    out[(size_t)T_DIM * B_DIM + (size_t)l * B_DIM + b] = h[l];
    out[(size_t)T_DIM * B_DIM + (size_t)L_DIM * B_DIM + (size_t)l * B_DIM + b] = c[l];
  }
}

extern "C" void kernel_launch(void* const* d_in, const int* in_sizes, int n_in,
                              void* d_out, int out_size, void* d_ws, size_t ws_size,
                              hipStream_t stream) {
  const float* x     = (const float*)d_in[0];
  const float* Wih0  = (const float*)d_in[1];
  const float* Wrest = (const float*)d_in[2];
  const float* Whh   = (const float*)d_in[3];
  const float* bih   = (const float*)d_in[4];
  const float* bhh   = (const float*)d_in[5];
  float* out = (float*)d_out;

  const size_t gx_bytes = (size_t)T_DIM * B_DIM * 4 * sizeof(float);  // 32 MiB
  if (ws_size >= gx_bytes) {
    float4* gx = (float4*)d_ws;
    gx0_kernel<<<(T_DIM * B_DIM) / 256, 256, 0, stream>>>(x, Wih0, bih, bhh, gx);
    lstm_scan_skew<<<B_DIM / 16, 64, 0, stream>>>(gx, Wrest, Whh, bih, bhh, out);
  } else {
    lstm_scan_fused<<<B_DIM / 64, 64, 0, stream>>>(x, Wih0, Wrest, Whh, bih, bhh, out);
  }
}

// Round 5
// 261.563 us; speedup vs baseline: 1.1253x; 1.1253x over previous
//
#include <hip/hip_runtime.h>

#define T_DIM 512
#define B_DIM 4096
#define F_DIM 16
#define L_DIM 4

typedef float f4 __attribute__((ext_vector_type(4)));

// ---------------- fast activations (exp2/rcp based, ~1 ulp) -----------------
__device__ __forceinline__ float fast_sigmoid(float x) {
  return __builtin_amdgcn_rcpf(1.0f + __builtin_amdgcn_exp2f(-1.44269504089f * x));
}
__device__ __forceinline__ float fast_tanh(float x) {
  return 1.0f - 2.0f * __builtin_amdgcn_rcpf(1.0f + __builtin_amdgcn_exp2f(2.88539008178f * x));
}

// lane(i) <- lane(i-1) within 16-lane DPP rows (row-boundary lanes are l=0,
// which ignore hin: wih=0).
__device__ __forceinline__ float dpp_prev(float v) {
  int r = __builtin_amdgcn_update_dpp(0, __builtin_bit_cast(int, v),
                                      0x111 /*row_shr:1*/, 0xf, 0xf, true);
  return __builtin_bit_cast(float, r);
}
// quad_perm DPP (compile-time ctrl): used for quad butterfly reduction.
template <int CTRL>
__device__ __forceinline__ float dpp_qp(float v) {
  int r = __builtin_amdgcn_update_dpp(0, __builtin_bit_cast(int, v),
                                      CTRL, 0xf, 0xf, true);
  return __builtin_bit_cast(float, r);
}

// Volatile global load: the compiler can neither sink nor drop it, and the
// destination value must live in registers until consumed.
__device__ __forceinline__ void ld_f4(f4& dst, unsigned voff, const f4* base) {
  asm volatile("global_load_dwordx4 %0, %1, %2"
               : "=v"(dst) : "v"(voff), "s"(base) : "memory");
}
// Wait for all outstanding VMEM; in-out constraints on the ring make every
// consumer of buf[] data-dependent on the wait (cannot be hoisted above it).
__device__ __forceinline__ void wait_ring(f4* buf) {
  asm volatile("s_waitcnt vmcnt(0)"
               : "+v"(buf[0]), "+v"(buf[1]), "+v"(buf[2]), "+v"(buf[3]),
                 "+v"(buf[4]), "+v"(buf[5]), "+v"(buf[6]), "+v"(buf[7])
               :: "memory");
}

// ---------------- phase 1: gx0 = x·Wih0^T + b, one thread per quarter-row ---
// Thread gidx handles float4 #gidx of x (row = gidx>>2, quarter q = gidx&3).
// Wave reads 1KB contiguous. Quad butterfly (DPP) reduces the 4 quarter-dots;
// lane q stores gate q -> consecutive dword stores. No strided access at all.
__global__ __launch_bounds__(256) void gx0_kernel(
    const f4* __restrict__ x4, const f4* __restrict__ W4,  // W4 = Wih0 as [4][4] f4
    const float* __restrict__ bih, const float* __restrict__ bhh,
    float* __restrict__ gx) {
  const int gidx = blockIdx.x * 256 + threadIdx.x;   // 0 .. T*B*4-1
  const int q = gidx & 3;
  f4 xv = x4[gidx];
  float p[4];
#pragma unroll
  for (int g = 0; g < 4; ++g) {
    f4 wv = W4[g * 4 + q];
    p[g] = fmaf(xv.x, wv.x, fmaf(xv.y, wv.y, fmaf(xv.z, wv.z, xv.w * wv.w)));
  }
#pragma unroll
  for (int g = 0; g < 4; ++g) {
    p[g] += dpp_qp<0xB1>(p[g]);   // quad_perm [1,0,3,2]: xor 1
    p[g] += dpp_qp<0x4E>(p[g]);   // quad_perm [2,3,0,1]: xor 2
  }
  float r = (q == 0) ? p[0] : (q == 1) ? p[1] : (q == 2) ? p[2] : p[3];
  gx[gidx] = r + bih[q] + bhh[q];
}

// ---------------- phase 2: layer-skewed scan, asm prefetch ring --------------
// Lane 4*cb + l: (chain b, layer l) at time t = k - l; h_{l-1}(t) via DPP.
// gx loads are issued as volatile asm one full 8-cell chunk ahead into a
// double-buffered register ring (R2/R3 showed the compiler sinks C++-level
// prefetch rings to their uses, exposing full load latency per cell).
__global__ __launch_bounds__(64, 1) void lstm_scan_skew(
    const f4* __restrict__ gx,        // [T*B] rows of (i,f,g,o), bias folded
    const float* __restrict__ Wrest,  // [3,4]
    const float* __restrict__ Whh,    // [4,4]
    const float* __restrict__ bih, const float* __restrict__ bhh,
    float* __restrict__ out) {
  const int lane = threadIdx.x;                    // 0..63
  const int l = lane & 3;                          // layer
  const int b = blockIdx.x * 16 + (lane >> 2);     // chain 0..4095
  const bool l0 = (l == 0);
  const float gsel = l0 ? 1.0f : 0.0f;             // gx only feeds layer 0

  float wih[4], whh[4], base[4];
#pragma unroll
  for (int g = 0; g < 4; ++g) {
    whh[g]  = Whh[l * 4 + g];
    wih[g]  = l0 ? 0.0f : Wrest[(l - 1) * 4 + g];
    base[g] = l0 ? 0.0f : (bih[l * 4 + g] + bhh[l * 4 + g]);
  }

  float* __restrict__ po = out + b;
  float h = 0.f, c = 0.f;

  // per-lane byte offsets within a chunk: chain offset + j*(B*16B)
  unsigned vj[8];
#pragma unroll
  for (int j = 0; j < 8; ++j) vj[j] = (unsigned)b * 16u + (unsigned)j * 65536u;

  f4 A[8], B[8];

  auto cell = [&](int k, f4 gq, bool guard) {
    float hin = dpp_prev(h);                       // h_{l-1}(t)
    float g0 = fmaf(whh[0], h, fmaf(wih[0], hin, fmaf(gsel, gq.x, base[0])));
    float g1 = fmaf(whh[1], h, fmaf(wih[1], hin, fmaf(gsel, gq.y, base[1])));
    float g2 = fmaf(whh[2], h, fmaf(wih[2], hin, fmaf(gsel, gq.z, base[2])));
    float g3 = fmaf(whh[3], h, fmaf(wih[3], hin, fmaf(gsel, gq.w, base[3])));
    float i_ = fast_sigmoid(g0);
    float f_ = fast_sigmoid(g1);
    float gg = fast_tanh(g2);
    float o_ = fast_sigmoid(g3);
    float cn = fmaf(f_, c, i_ * gg);
    float hn = o_ * fast_tanh(cn);
    if (guard) {
      const int t = k - l;
      const bool valid = (unsigned)t < (unsigned)T_DIM;
      c = valid ? cn : c;
      h = valid ? hn : h;
      if (l == 3 && valid) po[(size_t)t * B_DIM] = hn;
    } else {
      c = cn; h = hn;
      if (l == 3) po[(size_t)(k - 3) * B_DIM] = hn;
    }
  };
  auto cells8 = [&](int k0, f4* buf, bool guard) {
#pragma unroll
    for (int j = 0; j < 8; ++j) cell(k0 + j, buf[j], guard);
  };
  auto load8 = [&](f4* buf, int tbase) {
    const f4* p = gx + (size_t)tbase * B_DIM;
#pragma unroll
    for (int j = 0; j < 8; ++j) ld_f4(buf[j], vj[j], p);
  };

  load8(A, 0);                      // chunk 0 (t=0..7)
  wait_ring(A);
  load8(B, 8);                      // chunk 1
  cells8(0, A, true);               // warm-up k=0..7

#pragma unroll 1
  for (int n = 1; n < 63; n += 2) {
    wait_ring(B);
    load8(A, 8 * (n + 1));          // chunk n+1 (t<=504)
    cells8(8 * n, B, false);
    wait_ring(A);
    load8(B, 8 * (n + 2));          // chunk n+2 (t<=504)
    cells8(8 * (n + 1), A, false);
  }
  // chunk 63 (k=504..511):
  wait_ring(B);
  load8(A, 504);                    // drain-chunk data (values never consumed)
  cells8(504, B, false);
  // chunk 64 drain (k=512..519; only l>0 lanes still valid, gsel=0):
  wait_ring(A);
  cells8(512, A, true);

  // hn, cn: lane (b,l) holds h_l(T-1), c_l(T-1)
  po[(size_t)T_DIM * B_DIM + (size_t)l * B_DIM] = h;
  po[(size_t)T_DIM * B_DIM + (size_t)L_DIM * B_DIM + (size_t)l * B_DIM] = c;
}

// ---------------- fallback (no workspace): fused, unskewed -------------------
__global__ __launch_bounds__(64) void lstm_scan_fused(
    const float* __restrict__ x, const float* __restrict__ Wih0,
    const float* __restrict__ Wrest, const float* __restrict__ Whh,
    const float* __restrict__ bih, const float* __restrict__ bhh,
    float* __restrict__ out) {
  const int b = blockIdx.x * 64 + threadIdx.x;
  float whh_[4][4];
#pragma unroll
  for (int l = 0; l < 4; ++l)
#pragma unroll
    for (int g = 0; g < 4; ++g) whh_[l][g] = Whh[l * 4 + g];
  float wih_[3][4], base_[3][4];
#pragma unroll
  for (int l = 0; l < 3; ++l)
#pragma unroll
    for (int g = 0; g < 4; ++g) {
      wih_[l][g]  = Wrest[l * 4 + g];
      base_[l][g] = bih[(l + 1) * 4 + g] + bhh[(l + 1) * 4 + g];
    }
  float base0[4], wih0r[4][16];
#pragma unroll
  for (int g = 0; g < 4; ++g) {
    base0[g] = bih[g] + bhh[g];
#pragma unroll
    for (int i = 0; i < 16; ++i) wih0r[g][i] = Wih0[g * 16 + i];
  }
  float h[4] = {0.f,0.f,0.f,0.f}, c[4] = {0.f,0.f,0.f,0.f};
  for (int t = 0; t < T_DIM; ++t) {
    const float4* xr = (const float4*)x + ((size_t)t * B_DIM + b) * 4;
    float xs[16];
    *(float4*)&xs[0] = xr[0]; *(float4*)&xs[4] = xr[1];
    *(float4*)&xs[8] = xr[2]; *(float4*)&xs[12] = xr[3];
    float a0 = base0[0], a1 = base0[1], a2 = base0[2], a3 = base0[3];
#pragma unroll
    for (int i = 0; i < 16; ++i) {
      a0 = fmaf(wih0r[0][i], xs[i], a0);
      a1 = fmaf(wih0r[1][i], xs[i], a1);
      a2 = fmaf(wih0r[2][i], xs[i], a2);
      a3 = fmaf(wih0r[3][i], xs[i], a3);
    }
    float i_ = fast_sigmoid(fmaf(whh_[0][0], h[0], a0));
    float f_ = fast_sigmoid(fmaf(whh_[0][1], h[0], a1));
    float gg = fast_tanh(fmaf(whh_[0][2], h[0], a2));
    float o_ = fast_sigmoid(fmaf(whh_[0][3], h[0], a3));
    c[0] = fmaf(f_, c[0], i_ * gg);
    h[0] = o_ * fast_tanh(c[0]);
#pragma unroll
    for (int l = 1; l < 4; ++l) {
      float hin = h[l - 1];
      float gi = fmaf(whh_[l][0], h[l], fmaf(wih_[l-1][0], hin, base_[l-1][0]));
      float gf = fmaf(whh_[l][1], h[l], fmaf(wih_[l-1][1], hin, base_[l-1][1]));
      float gG = fmaf(whh_[l][2], h[l], fmaf(wih_[l-1][2], hin, base_[l-1][2]));
      float go = fmaf(whh_[l][3], h[l], fmaf(wih_[l-1][3], hin, base_[l-1][3]));
      float ii = fast_sigmoid(gi), ff = fast_sigmoid(gf);
      float gg2 = fast_tanh(gG), oo = fast_sigmoid(go);
      c[l] = fmaf(ff, c[l], ii * gg2);
      h[l] = oo * fast_tanh(c[l]);
    }
    out[(size_t)t * B_DIM + b] = h[3];
  }
#pragma unroll
  for (int l = 0; l < 4; ++l) {
    out[(size_t)T_DIM * B_DIM + (size_t)l * B_DIM + b] = h[l];
    out[(size_t)T_DIM * B_DIM + (size_t)L_DIM * B_DIM + (size_t)l * B_DIM + b] = c[l];
  }
}

extern "C" void kernel_launch(void* const* d_in, const int* in_sizes, int n_in,
                              void* d_out, int out_size, void* d_ws, size_t ws_size,
                              hipStream_t stream) {
  const float* x     = (const float*)d_in[0];
  const float* Wih0  = (const float*)d_in[1];
  const float* Wrest = (const float*)d_in[2];
  const float* Whh   = (const float*)d_in[3];
  const float* bih   = (const float*)d_in[4];
  const float* bhh   = (const float*)d_in[5];
  float* out = (float*)d_out;

  const size_t gx_bytes = (size_t)T_DIM * B_DIM * 4 * sizeof(float);  // 32 MiB
  if (ws_size >= gx_bytes) {
    float* gx = (float*)d_ws;
    const int nquarters = T_DIM * B_DIM * 4;       // 8,388,608
    gx0_kernel<<<nquarters / 256, 256, 0, stream>>>(
        (const f4*)x, (const f4*)Wih0, bih, bhh, gx);
    lstm_scan_skew<<<B_DIM / 16, 64, 0, stream>>>(
        (const f4*)gx, Wrest, Whh, bih, bhh, out);
  } else {
    lstm_scan_fused<<<B_DIM / 64, 64, 0, stream>>>(x, Wih0, Wrest, Whh, bih, bhh, out);
  }
}